// Round 2
// baseline (128.820 us; speedup 1.0000x reference)
//
#include <hip/hip_runtime.h>
#include <math.h>

#define QN 12
#define QDIM 4096
#define CHEB_TOL 2e-3f
// Swizzled LDS index (float2 units): pad 2 float2 per 16 elements.
// L(g) = g + 2*(g>>4). Conflict-free for the 1024-thread b128 pattern:
// lane i reads float-addr 8i + 4*(i>>2) (mod 32) -> each 16-lane phase has
// 2-way aliasing only (free per m136); neighbor XOR offsets only shift banks.
#define LSZ (QDIM + 2 * (QDIM / 16))

typedef unsigned int uint2_v __attribute__((ext_vector_type(2)));

// DPP lane permutations on the VALU pipe. All involutions; HW-verified R4-R9.
template <int CTRL>
__device__ __forceinline__ float dppf(float x) {
    int v = __builtin_amdgcn_update_dpp(0, __float_as_int(x), CTRL, 0xF, 0xF, false);
    return __int_as_float(v);
}
#define DPP_QX1 0xB1   // quad_perm [1,0,3,2]  : lane ^ 1
#define DPP_QX2 0x4E   // quad_perm [2,3,0,1]  : lane ^ 2
#define DPP_QX3 0x1B   // quad_perm [3,2,1,0]  : lane ^ 3
#define DPP_HM  0x141  // row_half_mirror      : lane ^ 7
#define DPP_R8  0x128  // row_ror:8            : lane ^ 8
__device__ __forceinline__ float dpp_x1(float x) { return dppf<DPP_QX1>(x); }
__device__ __forceinline__ float dpp_x2(float x) { return dppf<DPP_QX2>(x); }
__device__ __forceinline__ float dpp_x4(float x) { return dppf<DPP_HM>(dppf<DPP_QX3>(x)); }
__device__ __forceinline__ float dpp_x8(float x) { return dppf<DPP_R8>(x); }

// lane^16 / lane^32 on the VALU pipe via permlane*_swap (gfx950).
// v_permlane16_swap_b32 vdst,vsrc swaps ODD 16-lane rows of vdst with EVEN
// rows of vsrc. With both inputs = x: vdst' rows = [x0,x0,x2,x2],
// vsrc' rows = [x1,x1,x3,x3]  ->  value at lane^16 = row_odd ? vdst' : vsrc'.
// (Reintroduced: the old "scratch spills" note was at much higher VGPR
// pressure; current kernel is at 56/128. Watch VGPR_Count.)
__device__ __forceinline__ float pl16(float x, bool rowodd) {
    uint2_v r = __builtin_amdgcn_permlane16_swap(
        __float_as_uint(x), __float_as_uint(x), false, false);
    return __uint_as_float(rowodd ? r[0] : r[1]);
}
// v_permlane32_swap_b32: vdst row-pair {2,3} <-> vsrc row-pair {0,1}.
// With both inputs = x: vdst' = [x01,x01], vsrc' = [x23,x23] (row pairs)
// -> value at lane^32 = (lane>=32) ? vdst' : vsrc'.
__device__ __forceinline__ float pl32(float x, bool hihalf) {
    uint2_v r = __builtin_amdgcn_permlane32_swap(
        __float_as_uint(x), __float_as_uint(x), false, false);
    return __uint_as_float(hihalf ? r[0] : r[1]);
}

// One Chebyshev step: T_k = f*H*T1 - T2, written IN PLACE into T2 (register
// ping-pong). acc += (-i)^k * 2*J_k * T_k.  4 elem/thread, 1024 threads.
// Element bits 0..1: register; 2..5: DPP (lane xor 1,2,4,8);
// 6..7: permlane16/32_swap (VALU); 8..11: LDS (4 dims x 2 b128).
// LDS pipe budget/wave/step: 8 reads + 2 writes = 10 b128 (was 14).
#define CHEB_STEP(T1, T2, CURB, NXTB, KVAL, FVAL, ODD, WRITEB)                \
    {                                                                          \
        const int   k_ = (KVAL);                                               \
        const float f_ = (FVAL);                                               \
        float4 nbv[4][2];                                                      \
        _Pragma("unroll")                                                      \
        for (int j = 8; j < QN; ++j) {                                         \
            const int gx = g0 ^ (1 << j);                                      \
            const int hx = h0 ^ (1 << (j - 4));                                \
            const float4* q4 = (const float4*)((CURB) + gx + 2 * hx);          \
            nbv[j - 8][0] = q4[0];                                             \
            nbv[j - 8][1] = q4[1];                                             \
        }                                                                      \
        float hr[4], hi[4];                                                    \
        _Pragma("unroll")                                                      \
        for (int e = 0; e < 4; ++e) {                                          \
            hr[e] = dg[e] * T1[e].x + xj[0] * T1[e ^ 1].x                      \
                  + xj[1] * T1[e ^ 2].x;                                       \
            hi[e] = dg[e] * T1[e].y + xj[0] * T1[e ^ 1].y                      \
                  + xj[1] * T1[e ^ 2].y;                                       \
            hr[e] += xj[2] * dpp_x1(T1[e].x);  hi[e] += xj[2] * dpp_x1(T1[e].y); \
            hr[e] += xj[3] * dpp_x2(T1[e].x);  hi[e] += xj[3] * dpp_x2(T1[e].y); \
            hr[e] += xj[4] * dpp_x4(T1[e].x);  hi[e] += xj[4] * dpp_x4(T1[e].y); \
            hr[e] += xj[5] * dpp_x8(T1[e].x);  hi[e] += xj[5] * dpp_x8(T1[e].y); \
            hr[e] += xj[6] * pl16(T1[e].x, sel16); hi[e] += xj[6] * pl16(T1[e].y, sel16); \
            hr[e] += xj[7] * pl32(T1[e].x, sel32); hi[e] += xj[7] * pl32(T1[e].y, sel32); \
        }                                                                      \
        _Pragma("unroll")                                                      \
        for (int j = 8; j < QN; ++j) {                                         \
            _Pragma("unroll")                                                  \
            for (int m = 0; m < 2; ++m) {                                      \
                hr[2 * m]     += xj[j] * nbv[j - 8][m].x;                      \
                hi[2 * m]     += xj[j] * nbv[j - 8][m].y;                      \
                hr[2 * m + 1] += xj[j] * nbv[j - 8][m].z;                      \
                hi[2 * m + 1] += xj[j] * nbv[j - 8][m].w;                      \
            }                                                                  \
        }                                                                      \
        const float Jk2 = 2.0f * Jc[k_];                                       \
        const float c_  = (k_ & 2) ? Jk2 : -Jk2;                               \
        _Pragma("unroll")                                                      \
        for (int e = 0; e < 4; ++e) {                                          \
            const float tnx = f_ * hr[e] - T2[e].x;                            \
            const float tny = f_ * hi[e] - T2[e].y;                            \
            T2[e].x = tnx; T2[e].y = tny;                                      \
            if (ODD) {                                                         \
                acc[e].x = fmaf(-c_, tny, acc[e].x);                           \
                acc[e].y = fmaf( c_, tnx, acc[e].y);                           \
            } else {                                                           \
                acc[e].x = fmaf(-c_, tnx, acc[e].x);                           \
                acc[e].y = fmaf(-c_, tny, acc[e].y);                           \
            }                                                                  \
        }                                                                      \
        if (WRITEB) {                                                          \
            float4* w_ = (float4*)((NXTB) + l0);                               \
            w_[0] = make_float4(T2[0].x, T2[0].y, T2[1].x, T2[1].y);           \
            w_[1] = make_float4(T2[2].x, T2[2].y, T2[3].x, T2[3].y);           \
            __syncthreads();                                                   \
        }                                                                      \
    }

// Stage 1: psi_t = exp(-i t H)|init> via Chebyshev, one block per t.
__global__ __launch_bounds__(1024) void evolve_kernel(
    const int* __restrict__ init_state,
    const float* __restrict__ ts,
    const float* __restrict__ params_x,
    const float* __restrict__ params_zz,
    float2* __restrict__ psi_out)
{
    __shared__ __align__(16) float2 bufA[LSZ];
    __shared__ __align__(16) float2 bufB[LSZ];
    __shared__ float  Jc[128];
    __shared__ float  suLDS[160];
    __shared__ int    dsh;

    const int tid = threadIdx.x;          // 0..1023
    const int tI  = blockIdx.x;
    const float t = ts[tI];
    const int g0 = tid * 4;               // first owned element
    const int h0 = g0 >> 4;               // = tid >> 2
    const int l0 = g0 + 2 * h0;           // swizzled float2 base (even)
    const bool sel16 = (tid >> 4) & 1;    // 16-lane row parity
    const bool sel32 = (tid >> 5) & 1;    // wave half

    if (tid < 160) suLDS[tid] = 0.f;

    float xj[QN];
    float bound = 0.f;
#pragma unroll
    for (int j = 0; j < QN; ++j) { xj[j] = params_x[j]; bound += fabsf(xj[j]); }
    float zz[QN - 1];
#pragma unroll
    for (int i = 0; i < QN - 1; ++i) { zz[i] = params_zz[i]; bound += fabsf(zz[i]); }

    // diagonal (ZZ) term for the 4 owned elements
    float dg[4];
#pragma unroll
    for (int e = 0; e < 4; ++e) {
        const int g = g0 + e;
        float dv = 0.f;
#pragma unroll
        for (int i = 0; i < QN - 1; ++i) {
            const int flip = ((g >> i) ^ (g >> (i + 1))) & 1;
            dv += zz[i] * (1.0f - 2.0f * (float)flip);
        }
        dg[e] = dv;
    }

    const float theta = t * bound;
    int dmax = (int)ceilf(theta + 5.0f * cbrtf(theta)) + 6;
    if (dmax < 8) dmax = 8;
    if (dmax > 126) dmax = 126;

    // Bessel J_k(theta) via Miller backward recurrence (fp64, rolling).
    {
        const int M = dmax + 24;
        const double th = (double)fmaxf(theta, 1e-6f);
        const double invth = 1.0 / th;
        double jkp1 = 0.0, jk = 1e-30, mine = 0.0, nrm = 0.0, suf = 0.0, su_own = 0.0;
        for (int k = M; k >= 0; --k) {
            suf += fabs(jk);
            if (k == tid) { mine = jk; su_own = suf; }
            if (k == 0) nrm += jk;
            else if ((k & 1) == 0) nrm += 2.0 * jk;
            const double jkm1 = (2.0 * (double)k * invth) * jk - jkp1;
            jkp1 = jk; jk = jkm1;
            if (fabs(jk) > 1e250) {
                jk *= 1e-250; jkp1 *= 1e-250; mine *= 1e-250;
                nrm *= 1e-250; suf *= 1e-250; su_own *= 1e-250;
            }
        }
        const double anrm = fabs(nrm);
        if (tid <= dmax) Jc[tid] = (float)(mine / nrm);
        if (tid < 160) suLDS[tid] = (float)(su_own / anrm);
    }

    const int is = init_state[0];
    const float inv_s = 1.0f / bound;

    float2 ta[4];    // T_{k-1}
    float2 tb[4];    // T_{k-2} -> T_k in place
    float2 acc[4];
#pragma unroll
    for (int e = 0; e < 4; ++e) {
        const float v = (g0 + e == is) ? 1.0f : 0.0f;
        ta[e] = make_float2(v, 0.f);
        tb[e] = make_float2(0.f, 0.f);
    }
    {
        float4* w0 = (float4*)(bufA + l0);
        w0[0] = make_float4(ta[0].x, ta[0].y, ta[1].x, ta[1].y);
        w0[1] = make_float4(ta[2].x, ta[2].y, ta[3].x, ta[3].y);
    }
    __syncthreads();   // Jc/suLDS/bufA visible

    // adaptive degree: smallest d with suffix(d+1) < tol (wave-0 double ballot)
    if (tid < 64) {
        const bool p0 = suLDS[tid + 1] < CHEB_TOL;
        const bool p1 = suLDS[tid + 65] < CHEB_TOL;
        const unsigned long long b0 = __ballot(p0);
        const unsigned long long b1 = __ballot(p1);
        if (tid == 0) {
            int dd;
            if (b0) dd = __ffsll(b0) - 1;
            else if (b1) dd = 64 + __ffsll(b1) - 1;
            else dd = dmax;
            if (dd < 2) dd = 2;
            if (dd > dmax) dd = dmax;
            dsh = dd;
        }
    }
    __syncthreads();
    const int d = dsh;

#pragma unroll
    for (int e = 0; e < 4; ++e) acc[e] = make_float2(Jc[0] * ta[e].x, 0.f);

    // k=1 (f = 1/s), then pairs with in-place register ping-pong.
    // Final step (k==d) skips the LDS write-back + barrier: nothing reads it.
    CHEB_STEP(ta, tb, bufA, bufB, 1, inv_s, true, (1 < d));
    const float f2 = 2.0f * inv_s;
    int k = 2;
    for (; k + 1 <= d; k += 2) {
        CHEB_STEP(tb, ta, bufB, bufA, k,     f2, false, true);
        CHEB_STEP(ta, tb, bufA, bufB, k + 1, f2, true,  (k + 1 < d));
    }
    if (k <= d) {
        CHEB_STEP(tb, ta, bufB, bufA, k, f2, false, false);
    }

    float4* o = (float4*)(psi_out + tI * QDIM + g0);
    o[0] = make_float4(acc[0].x, acc[0].y, acc[1].x, acc[1].y);
    o[1] = make_float4(acc[2].x, acc[2].y, acc[3].x, acc[3].y);
}

// Single-qubit basis gate applied to a (lo,hi) amplitude pair.
// p==0: H-like (X basis), p==1: Y basis, p==2: identity.
__device__ __forceinline__ void apply_g(int p, float2& lo, float2& hi) {
    const float s = 0.70710678118654752440f;
    const float2 a = lo, c = hi;
    if (p == 0) {
        lo = make_float2(s * (a.x + c.x), s * (a.y + c.y));
        hi = make_float2(s * (a.x - c.x), s * (a.y - c.y));
    } else if (p == 1) {
        lo = make_float2(s * (a.x + c.y), s * (a.y - c.x));
        hi = make_float2(s * (a.x - c.y), s * (a.y + c.x));
    }
}

// Stage 2: one block per (t, b). Fused adjacent-bit-pair passes: each thread
// owns a closed 4-element group per pass (no intra-pass hazards, 1 barrier
// per pass, 6 passes instead of 12). Swizzled LDS layout (same L(g) as
// evolve) keeps the qa=0 b128 pass conflict-free. Gate for pauli index i
// acts on bit position QN-1-i; gates on different bits commute, so adjacent
// pairing is valid. Both-Z pairs are skipped entirely.
__global__ __launch_bounds__(1024) void measure_kernel(
    const float2* __restrict__ psi,
    const int* __restrict__ pauli_obs,
    const int* __restrict__ indices,
    float* __restrict__ out)
{
    __shared__ __align__(16) float2 st[LSZ];
    const int tid = threadIdx.x;          // 0..1023
    const int blk = blockIdx.x;
    const int tI = blk >> 5;
    const int b  = blk & 31;

    const int g0 = tid * 4;
    const int l0 = g0 + 2 * (g0 >> 4);
    {
        const float4* src = (const float4*)(psi + tI * QDIM + g0);
        float4* w = (float4*)(st + l0);
        w[0] = src[0];
        w[1] = src[1];
    }
    __syncthreads();

#pragma unroll
    for (int qp = 0; qp < QN / 2; ++qp) {
        const int qa = 2 * qp;                                 // bits qa, qa+1
        const int pa = pauli_obs[b * QN + (QN - 1 - qa)];
        const int pb = pauli_obs[b * QN + (QN - 2 - qa)];
        if (pa == 2 && pb == 2) continue;
        float2 v[4];
        if (qa == 0) {
            // group = own 4 consecutive elements: 2 x b128, conflict-free
            float4* r = (float4*)(st + l0);
            const float4 r0 = r[0], r1 = r[1];
            v[0] = make_float2(r0.x, r0.y); v[1] = make_float2(r0.z, r0.w);
            v[2] = make_float2(r1.x, r1.y); v[3] = make_float2(r1.z, r1.w);
            apply_g(pa, v[0], v[1]); apply_g(pa, v[2], v[3]);
            apply_g(pb, v[0], v[2]); apply_g(pb, v[1], v[3]);
            r[0] = make_float4(v[0].x, v[0].y, v[1].x, v[1].y);
            r[1] = make_float4(v[2].x, v[2].y, v[3].x, v[3].y);
        } else {
            const int m = (1 << qa) - 1;
            const int base = ((tid & ~m) << 2) | (tid & m);
            int li[4];
#pragma unroll
            for (int kk = 0; kk < 4; ++kk) {
                const int g = base + (kk << qa);
                li[kk] = g + 2 * (g >> 4);
                v[kk] = st[li[kk]];
            }
            apply_g(pa, v[0], v[1]); apply_g(pa, v[2], v[3]);
            apply_g(pb, v[0], v[2]); apply_g(pb, v[1], v[3]);
#pragma unroll
            for (int kk = 0; kk < 4; ++kk) st[li[kk]] = v[kk];
        }
        __syncthreads();
    }

    if (tid < 256) {
        const int oi = (tI * 32 + b) * 256 + tid;
        const int idx = indices[oi];
        const float2 vv = st[idx + 2 * (idx >> 4)];
        out[oi] = vv.x * vv.x + vv.y * vv.y;
    }
}

extern "C" void kernel_launch(void* const* d_in, const int* in_sizes, int n_in,
                              void* d_out, int out_size, void* d_ws, size_t ws_size,
                              hipStream_t stream) {
    const int*   init_state = (const int*)d_in[0];
    const float* ts         = (const float*)d_in[1];
    const int*   pauli_obs  = (const int*)d_in[2];
    const int*   indices    = (const int*)d_in[3];
    const float* params_x   = (const float*)d_in[4];
    const float* params_zz  = (const float*)d_in[5];
    float*  out = (float*)d_out;
    float2* psi = (float2*)d_ws;   // 8 * 4096 * 8 B = 256 KB scratch

    hipLaunchKernelGGL(evolve_kernel, dim3(8), dim3(1024), 0, stream,
                       init_state, ts, params_x, params_zz, psi);
    hipLaunchKernelGGL(measure_kernel, dim3(8 * 32), dim3(1024), 0, stream,
                       psi, pauli_obs, indices, out);
}

// Round 3
// 96.750 us; speedup vs baseline: 1.3315x; 1.3315x over previous
//
#include <hip/hip_runtime.h>
#include <math.h>

#define QN 12
#define QDIM 4096
#define CHEB_TOL 2e-3f
// Swizzled LDS index (float2 units) for the MEASURE kernel only.
#define LSZ (QDIM + 2 * (QDIM / 16))

// DPP lane permutations on the VALU pipe. All involutions; HW-verified R4-R9.
// (permlane16/32_swap: R2 measured -33% — copies+cndmask+lost load hoisting.
//  Dead path, do not reintroduce.)
template <int CTRL>
__device__ __forceinline__ float dppf(float x) {
    int v = __builtin_amdgcn_update_dpp(0, __float_as_int(x), CTRL, 0xF, 0xF, false);
    return __int_as_float(v);
}
#define DPP_QX1 0xB1   // quad_perm [1,0,3,2]  : lane ^ 1
#define DPP_QX2 0x4E   // quad_perm [2,3,0,1]  : lane ^ 2
#define DPP_QX3 0x1B   // quad_perm [3,2,1,0]  : lane ^ 3
#define DPP_HM  0x141  // row_half_mirror      : lane ^ 7
#define DPP_R8  0x128  // row_ror:8            : lane ^ 8
__device__ __forceinline__ float dpp_x1(float x) { return dppf<DPP_QX1>(x); }
__device__ __forceinline__ float dpp_x2(float x) { return dppf<DPP_QX2>(x); }
__device__ __forceinline__ float dpp_x4(float x) { return dppf<DPP_HM>(dppf<DPP_QX3>(x)); }
__device__ __forceinline__ float dpp_x8(float x) { return dppf<DPP_R8>(x); }

// One Chebyshev step, REAL arithmetic (H real + real start => all T_k real;
// the (-i)^k twiddle only routes T_k into acc.x or acc.y).
// T_k = f*H*T1 - T2 written IN PLACE into T2.  4 elem/thread, 1024 threads.
// Element bits 0..1: register; 2..5: DPP (lane xor 1,2,4,8); 6..11: LDS.
// LDS budget/wave/step: 6 b128 reads + 1 b128 write  (R1 complex had 14).
// No swizzle needed: XOR offsets are >=64 floats = whole 256B rows, so each
// 16-lane phase of a contiguous b128 covers all 32 banks exactly once.
#define CHEB_STEP(T1, T2, CURB, NXTB, KVAL, FVAL, ODD, WRITEB)                \
    {                                                                          \
        const int   k_ = (KVAL);                                               \
        const float f_ = (FVAL);                                               \
        float4 nbv[6];                                                         \
        _Pragma("unroll")                                                      \
        for (int j = 6; j < QN; ++j)                                           \
            nbv[j - 6] = *(const float4*)((CURB) + (g0 ^ (1 << j)));           \
        float hr[4];                                                           \
        _Pragma("unroll")                                                      \
        for (int e = 0; e < 4; ++e) {                                          \
            hr[e] = dg[e] * T1[e] + xj[0] * T1[e ^ 1] + xj[1] * T1[e ^ 2];     \
            hr[e] += xj[2] * dpp_x1(T1[e]);                                    \
            hr[e] += xj[3] * dpp_x2(T1[e]);                                    \
            hr[e] += xj[4] * dpp_x4(T1[e]);                                    \
            hr[e] += xj[5] * dpp_x8(T1[e]);                                    \
        }                                                                      \
        _Pragma("unroll")                                                      \
        for (int j = 6; j < QN; ++j) {                                         \
            hr[0] += xj[j] * nbv[j - 6].x;                                     \
            hr[1] += xj[j] * nbv[j - 6].y;                                     \
            hr[2] += xj[j] * nbv[j - 6].z;                                     \
            hr[3] += xj[j] * nbv[j - 6].w;                                     \
        }                                                                      \
        const float Jk2 = 2.0f * Jc[k_];                                       \
        const float c_  = (k_ & 2) ? Jk2 : -Jk2;                               \
        _Pragma("unroll")                                                      \
        for (int e = 0; e < 4; ++e) {                                          \
            const float tn = f_ * hr[e] - T2[e];                               \
            T2[e] = tn;                                                        \
            if (ODD) acc[e].y = fmaf( c_, tn, acc[e].y);                       \
            else     acc[e].x = fmaf(-c_, tn, acc[e].x);                       \
        }                                                                      \
        if (WRITEB) {                                                          \
            *(float4*)((NXTB) + g0) =                                          \
                make_float4(T2[0], T2[1], T2[2], T2[3]);                       \
            __syncthreads();                                                   \
        }                                                                      \
    }

// Stage 1: psi_t = exp(-i t H)|init> via Chebyshev, one block per t.
__global__ __launch_bounds__(1024) void evolve_kernel(
    const int* __restrict__ init_state,
    const float* __restrict__ ts,
    const float* __restrict__ params_x,
    const float* __restrict__ params_zz,
    float2* __restrict__ psi_out)
{
    __shared__ __align__(16) float bufA[QDIM];
    __shared__ __align__(16) float bufB[QDIM];
    __shared__ float  Jc[128];
    __shared__ float  suLDS[160];
    __shared__ int    dsh;

    const int tid = threadIdx.x;          // 0..1023
    const int tI  = blockIdx.x;
    const float t = ts[tI];
    const int g0 = tid * 4;               // first owned element

    if (tid < 160) suLDS[tid] = 0.f;

    float xj[QN];
    float bound = 0.f;
#pragma unroll
    for (int j = 0; j < QN; ++j) { xj[j] = params_x[j]; bound += fabsf(xj[j]); }
    float zz[QN - 1];
#pragma unroll
    for (int i = 0; i < QN - 1; ++i) { zz[i] = params_zz[i]; bound += fabsf(zz[i]); }

    // diagonal (ZZ) term for the 4 owned elements
    float dg[4];
#pragma unroll
    for (int e = 0; e < 4; ++e) {
        const int g = g0 + e;
        float dv = 0.f;
#pragma unroll
        for (int i = 0; i < QN - 1; ++i) {
            const int flip = ((g >> i) ^ (g >> (i + 1))) & 1;
            dv += zz[i] * (1.0f - 2.0f * (float)flip);
        }
        dg[e] = dv;
    }

    const float theta = t * bound;
    int dmax = (int)ceilf(theta + 5.0f * cbrtf(theta)) + 6;
    if (dmax < 8) dmax = 8;
    if (dmax > 126) dmax = 126;

    // Bessel J_k(theta) via Miller backward recurrence (fp64, rolling).
    {
        const int M = dmax + 24;
        const double th = (double)fmaxf(theta, 1e-6f);
        const double invth = 1.0 / th;
        double jkp1 = 0.0, jk = 1e-30, mine = 0.0, nrm = 0.0, suf = 0.0, su_own = 0.0;
        for (int k = M; k >= 0; --k) {
            suf += fabs(jk);
            if (k == tid) { mine = jk; su_own = suf; }
            if (k == 0) nrm += jk;
            else if ((k & 1) == 0) nrm += 2.0 * jk;
            const double jkm1 = (2.0 * (double)k * invth) * jk - jkp1;
            jkp1 = jk; jk = jkm1;
            if (fabs(jk) > 1e250) {
                jk *= 1e-250; jkp1 *= 1e-250; mine *= 1e-250;
                nrm *= 1e-250; suf *= 1e-250; su_own *= 1e-250;
            }
        }
        const double anrm = fabs(nrm);
        if (tid <= dmax) Jc[tid] = (float)(mine / nrm);
        if (tid < 160) suLDS[tid] = (float)(su_own / anrm);
    }

    const int is = init_state[0];
    const float inv_s = 1.0f / bound;

    float ta[4];     // T_{k-1}   (real)
    float tb[4];     // T_{k-2} -> T_k in place  (real)
    float2 acc[4];   // complex accumulator
#pragma unroll
    for (int e = 0; e < 4; ++e) {
        ta[e] = (g0 + e == is) ? 1.0f : 0.0f;
        tb[e] = 0.f;
    }
    *(float4*)(bufA + g0) = make_float4(ta[0], ta[1], ta[2], ta[3]);
    __syncthreads();   // Jc/suLDS/bufA visible

    // adaptive degree: smallest d with suffix(d+1) < tol (wave-0 double ballot)
    if (tid < 64) {
        const bool p0 = suLDS[tid + 1] < CHEB_TOL;
        const bool p1 = suLDS[tid + 65] < CHEB_TOL;
        const unsigned long long b0 = __ballot(p0);
        const unsigned long long b1 = __ballot(p1);
        if (tid == 0) {
            int dd;
            if (b0) dd = __ffsll(b0) - 1;
            else if (b1) dd = 64 + __ffsll(b1) - 1;
            else dd = dmax;
            if (dd < 2) dd = 2;
            if (dd > dmax) dd = dmax;
            dsh = dd;
        }
    }
    __syncthreads();
    const int d = dsh;

#pragma unroll
    for (int e = 0; e < 4; ++e) acc[e] = make_float2(Jc[0] * ta[e], 0.f);

    // k=1 (f = 1/s), then pairs with in-place register ping-pong.
    // Final step (k==d) skips the LDS write-back + barrier: nothing reads it.
    CHEB_STEP(ta, tb, bufA, bufB, 1, inv_s, true, (1 < d));
    const float f2 = 2.0f * inv_s;
    int k = 2;
    for (; k + 1 <= d; k += 2) {
        CHEB_STEP(tb, ta, bufB, bufA, k,     f2, false, true);
        CHEB_STEP(ta, tb, bufA, bufB, k + 1, f2, true,  (k + 1 < d));
    }
    if (k <= d) {
        CHEB_STEP(tb, ta, bufB, bufA, k, f2, false, false);
    }

    float4* o = (float4*)(psi_out + tI * QDIM + g0);
    o[0] = make_float4(acc[0].x, acc[0].y, acc[1].x, acc[1].y);
    o[1] = make_float4(acc[2].x, acc[2].y, acc[3].x, acc[3].y);
}

// Single-qubit basis gate applied to a (lo,hi) amplitude pair.
// p==0: H-like (X basis), p==1: Y basis, p==2: identity.
__device__ __forceinline__ void apply_g(int p, float2& lo, float2& hi) {
    const float s = 0.70710678118654752440f;
    const float2 a = lo, c = hi;
    if (p == 0) {
        lo = make_float2(s * (a.x + c.x), s * (a.y + c.y));
        hi = make_float2(s * (a.x - c.x), s * (a.y - c.y));
    } else if (p == 1) {
        lo = make_float2(s * (a.x + c.y), s * (a.y - c.x));
        hi = make_float2(s * (a.x - c.y), s * (a.y + c.x));
    }
}

// Stage 2: one block per (t, b). Fused adjacent-bit-pair passes: each thread
// owns a closed 4-element group per pass (no intra-pass hazards, 1 barrier
// per pass, 6 passes instead of 12). Swizzled LDS layout keeps the qa=0
// b128 pass conflict-free. Gate for pauli index i acts on bit QN-1-i;
// gates on different bits commute, so adjacent pairing is valid.
__global__ __launch_bounds__(1024) void measure_kernel(
    const float2* __restrict__ psi,
    const int* __restrict__ pauli_obs,
    const int* __restrict__ indices,
    float* __restrict__ out)
{
    __shared__ __align__(16) float2 st[LSZ];
    const int tid = threadIdx.x;          // 0..1023
    const int blk = blockIdx.x;
    const int tI = blk >> 5;
    const int b  = blk & 31;

    const int g0 = tid * 4;
    const int l0 = g0 + 2 * (g0 >> 4);
    {
        const float4* src = (const float4*)(psi + tI * QDIM + g0);
        float4* w = (float4*)(st + l0);
        w[0] = src[0];
        w[1] = src[1];
    }
    __syncthreads();

#pragma unroll
    for (int qp = 0; qp < QN / 2; ++qp) {
        const int qa = 2 * qp;                                 // bits qa, qa+1
        const int pa = pauli_obs[b * QN + (QN - 1 - qa)];
        const int pb = pauli_obs[b * QN + (QN - 2 - qa)];
        if (pa == 2 && pb == 2) continue;
        float2 v[4];
        if (qa == 0) {
            // group = own 4 consecutive elements: 2 x b128, conflict-free
            float4* r = (float4*)(st + l0);
            const float4 r0 = r[0], r1 = r[1];
            v[0] = make_float2(r0.x, r0.y); v[1] = make_float2(r0.z, r0.w);
            v[2] = make_float2(r1.x, r1.y); v[3] = make_float2(r1.z, r1.w);
            apply_g(pa, v[0], v[1]); apply_g(pa, v[2], v[3]);
            apply_g(pb, v[0], v[2]); apply_g(pb, v[1], v[3]);
            r[0] = make_float4(v[0].x, v[0].y, v[1].x, v[1].y);
            r[1] = make_float4(v[2].x, v[2].y, v[3].x, v[3].y);
        } else {
            const int m = (1 << qa) - 1;
            const int base = ((tid & ~m) << 2) | (tid & m);
            int li[4];
#pragma unroll
            for (int kk = 0; kk < 4; ++kk) {
                const int g = base + (kk << qa);
                li[kk] = g + 2 * (g >> 4);
                v[kk] = st[li[kk]];
            }
            apply_g(pa, v[0], v[1]); apply_g(pa, v[2], v[3]);
            apply_g(pb, v[0], v[2]); apply_g(pb, v[1], v[3]);
#pragma unroll
            for (int kk = 0; kk < 4; ++kk) st[li[kk]] = v[kk];
        }
        __syncthreads();
    }

    if (tid < 256) {
        const int oi = (tI * 32 + b) * 256 + tid;
        const int idx = indices[oi];
        const float2 vv = st[idx + 2 * (idx >> 4)];
        out[oi] = vv.x * vv.x + vv.y * vv.y;
    }
}

extern "C" void kernel_launch(void* const* d_in, const int* in_sizes, int n_in,
                              void* d_out, int out_size, void* d_ws, size_t ws_size,
                              hipStream_t stream) {
    const int*   init_state = (const int*)d_in[0];
    const float* ts         = (const float*)d_in[1];
    const int*   pauli_obs  = (const int*)d_in[2];
    const int*   indices    = (const int*)d_in[3];
    const float* params_x   = (const float*)d_in[4];
    const float* params_zz  = (const float*)d_in[5];
    float*  out = (float*)d_out;
    float2* psi = (float2*)d_ws;   // 8 * 4096 * 8 B = 256 KB scratch

    hipLaunchKernelGGL(evolve_kernel, dim3(8), dim3(1024), 0, stream,
                       init_state, ts, params_x, params_zz, psi);
    hipLaunchKernelGGL(measure_kernel, dim3(8 * 32), dim3(1024), 0, stream,
                       psi, pauli_obs, indices, out);
}